// Round 2
// baseline (2284.281 us; speedup 1.0000x reference)
//
#include <hip/hip_runtime.h>
#include <math.h>

// ---------------------------------------------------------------------------
// spline_net: 2-layer SplineConv (linear spline, 1D pseudo-coords, 2 knots)
//   layer1: h = elu( mean_agg( (1-u)*x@W1[0][src] + u*x@W1[1][src] ) + x@root1 + b1 )
//   layer2: out =    mean_agg( (1-u)*h@W2[0][src] + u*h@W2[1][src] ) + h@root2 + b2
// N=100000, F_IN=128, HID=16, C=10, E=1600000
// ---------------------------------------------------------------------------

// GEMM1: h01[n][0:16]=x@W1[0], h01[n][16:32]=x@W1[1], xr[n][0:16]=x@root1
__global__ __launch_bounds__(256) void gemm1_kernel(
    const float* __restrict__ x, const float* __restrict__ W1,
    const float* __restrict__ root1, float* __restrict__ h01,
    float* __restrict__ xr, int N)
{
    __shared__ float Ws[128][48];
    int tid = threadIdx.x;
    for (int idx = tid; idx < 128 * 16; idx += 256) {
        int i = idx >> 4, j = idx & 15;
        Ws[i][j]      = W1[i * 16 + j];          // W1[0][i][j]
        Ws[i][16 + j] = W1[2048 + i * 16 + j];   // W1[1][i][j]
        Ws[i][32 + j] = root1[i * 16 + j];
    }
    __syncthreads();
    int n = blockIdx.x * 256 + tid;
    if (n >= N) return;

    float acc[48];
#pragma unroll
    for (int j = 0; j < 48; ++j) acc[j] = 0.f;

    const float4* xrow = (const float4*)(x + (size_t)n * 128);
#pragma unroll 1
    for (int k4 = 0; k4 < 32; ++k4) {
        float4 xv = xrow[k4];
        int k = k4 * 4;
#pragma unroll
        for (int j = 0; j < 48; ++j) {
            acc[j] += xv.x * Ws[k][j] + xv.y * Ws[k + 1][j]
                    + xv.z * Ws[k + 2][j] + xv.w * Ws[k + 3][j];
        }
    }
    float4* out01 = (float4*)(h01 + (size_t)n * 32);
#pragma unroll
    for (int q = 0; q < 8; ++q)
        out01[q] = make_float4(acc[q * 4], acc[q * 4 + 1], acc[q * 4 + 2], acc[q * 4 + 3]);
    float4* outr = (float4*)(xr + (size_t)n * 16);
#pragma unroll
    for (int q = 0; q < 4; ++q)
        outr[q] = make_float4(acc[32 + q * 4], acc[33 + q * 4], acc[34 + q * 4], acc[35 + q * 4]);
}

// Edge pass 1: gather h01[src], lerp by w1, atomic-scatter into agg1[dst]; deg[dst]+=1
__global__ __launch_bounds__(256) void edge1_kernel(
    const int* __restrict__ ei, const float* __restrict__ ea,
    const float* __restrict__ h01, float* __restrict__ agg1,
    float* __restrict__ deg, int E)
{
    int e = blockIdx.x * 256 + threadIdx.x;
    if (e >= E) return;
    int s = ei[e];
    int d = ei[E + e];
    float w1 = ea[e];
    const float4* hp = (const float4*)(h01 + (size_t)s * 32);
    float m[16];
#pragma unroll
    for (int q = 0; q < 4; ++q) {
        float4 a = hp[q];        // h0 block
        float4 b = hp[4 + q];    // h1 block
        m[q * 4 + 0] = a.x + w1 * (b.x - a.x);
        m[q * 4 + 1] = a.y + w1 * (b.y - a.y);
        m[q * 4 + 2] = a.z + w1 * (b.z - a.z);
        m[q * 4 + 3] = a.w + w1 * (b.w - a.w);
    }
    float* ap = agg1 + (size_t)d * 16;
#pragma unroll
    for (int c = 0; c < 16; ++c) atomicAdd(ap + c, m[c]);
    atomicAdd(deg + d, 1.0f);
}

// Finalize 1 + fused layer-2 node transforms:
//   h = elu(agg1/max(deg,1) + xr + b1)
//   g01[n][0:10]=h@W2[0], g01[n][10:20]=h@W2[1], hrb[n][0:10]=h@root2+b2
__global__ __launch_bounds__(256) void finalize1_kernel(
    const float* __restrict__ agg1, const float* __restrict__ deg,
    const float* __restrict__ xr, const float* __restrict__ b1,
    const float* __restrict__ W2, const float* __restrict__ root2,
    const float* __restrict__ b2, float* __restrict__ g01,
    float* __restrict__ hrb, int N)
{
    __shared__ float w2s[320];   // W2[2][16][10]
    __shared__ float r2s[160];   // root2[16][10]
    __shared__ float b1s[16];
    __shared__ float b2s[10];
    int tid = threadIdx.x;
    // BUGFIX r1: block=256 but W2 has 320 elems — previous `if (tid<320)`
    // left w2s[256:320] uninitialized. Strided loop covers all.
    for (int idx = tid; idx < 320; idx += 256) w2s[idx] = W2[idx];
    if (tid < 160) r2s[tid] = root2[tid];
    if (tid < 16)  b1s[tid] = b1[tid];
    if (tid < 10)  b2s[tid] = b2[tid];
    __syncthreads();
    int n = blockIdx.x * 256 + tid;
    if (n >= N) return;

    float invd = 1.0f / fmaxf(deg[n], 1.0f);
    float h[16];
#pragma unroll
    for (int c = 0; c < 16; ++c) {
        float v = agg1[(size_t)n * 16 + c] * invd + xr[(size_t)n * 16 + c] + b1s[c];
        h[c] = v > 0.f ? v : expm1f(v);   // elu, alpha=1
    }
    float g0[10], g1[10], hr[10];
#pragma unroll
    for (int j = 0; j < 10; ++j) { g0[j] = 0.f; g1[j] = 0.f; hr[j] = 0.f; }
#pragma unroll
    for (int i = 0; i < 16; ++i) {
#pragma unroll
        for (int j = 0; j < 10; ++j) {
            g0[j] += h[i] * w2s[i * 10 + j];
            g1[j] += h[i] * w2s[160 + i * 10 + j];
            hr[j] += h[i] * r2s[i * 10 + j];
        }
    }
    float* gp = g01 + (size_t)n * 20;
#pragma unroll
    for (int j = 0; j < 10; ++j) { gp[j] = g0[j]; gp[10 + j] = g1[j]; }
    float* hp = hrb + (size_t)n * 10;
#pragma unroll
    for (int j = 0; j < 10; ++j) hp[j] = hr[j] + b2s[j];
}

// Edge pass 2: gather g01[src] (20 floats), lerp, atomic-scatter into agg2[dst]
__global__ __launch_bounds__(256) void edge2_kernel(
    const int* __restrict__ ei, const float* __restrict__ ea,
    const float* __restrict__ g01, float* __restrict__ agg2, int E)
{
    int e = blockIdx.x * 256 + threadIdx.x;
    if (e >= E) return;
    int s = ei[e];
    int d = ei[E + e];
    float w1 = ea[e];
    alignas(16) float r[20];
    const float4* gp = (const float4*)(g01 + (size_t)s * 20);  // 80B rows, 16B aligned
#pragma unroll
    for (int q = 0; q < 5; ++q) ((float4*)r)[q] = gp[q];
    float* ap = agg2 + (size_t)d * 10;
#pragma unroll
    for (int j = 0; j < 10; ++j) atomicAdd(ap + j, r[j] + w1 * (r[10 + j] - r[j]));
}

// Finalize 2: out = agg2/max(deg,1) + hrb   (element-per-thread, N*10 elems)
__global__ __launch_bounds__(256) void finalize2_kernel(
    const float* __restrict__ agg2, const float* __restrict__ deg,
    const float* __restrict__ hrb, float* __restrict__ out, int N)
{
    int idx = blockIdx.x * 256 + threadIdx.x;
    if (idx >= N * 10) return;
    int n = idx / 10;
    float invd = 1.0f / fmaxf(deg[n], 1.0f);
    out[idx] = agg2[idx] * invd + hrb[idx];
}

extern "C" void kernel_launch(void* const* d_in, const int* in_sizes, int n_in,
                              void* d_out, int out_size, void* d_ws, size_t ws_size,
                              hipStream_t stream)
{
    const float* x     = (const float*)d_in[0];
    const int*   ei    = (const int*)d_in[1];   // (2,E) int32
    const float* ea    = (const float*)d_in[2]; // (E,1)
    const float* W1    = (const float*)d_in[3]; // (2,128,16)
    const float* root1 = (const float*)d_in[4]; // (128,16)
    const float* b1    = (const float*)d_in[5]; // (16,)
    const float* W2    = (const float*)d_in[6]; // (2,16,10)
    const float* root2 = (const float*)d_in[7]; // (16,10)
    const float* b2    = (const float*)d_in[8]; // (10,)
    float* out = (float*)d_out;

    int N = in_sizes[0] / 128;
    int E = in_sizes[2];   // edge_attr flat size = E

    // workspace layout (floats): total N*105 = 42 MB for N=100k
    float* ws   = (float*)d_ws;
    float* h01  = ws;                          // N*32
    float* xr   = h01  + (size_t)N * 32;       // N*16
    float* agg1 = xr   + (size_t)N * 16;       // N*16
    float* deg  = agg1 + (size_t)N * 16;       // N
    float* g01  = deg  + (size_t)N;            // N*20
    float* hrb  = g01  + (size_t)N * 20;       // N*10
    float* agg2 = hrb  + (size_t)N * 10;       // N*10

    hipMemsetAsync(agg1, 0, (size_t)N * 16 * sizeof(float), stream);
    hipMemsetAsync(deg,  0, (size_t)N * sizeof(float), stream);
    hipMemsetAsync(agg2, 0, (size_t)N * 10 * sizeof(float), stream);

    int nb_n = (N + 255) / 256;
    int nb_e = (E + 255) / 256;
    gemm1_kernel<<<nb_n, 256, 0, stream>>>(x, W1, root1, h01, xr, N);
    edge1_kernel<<<nb_e, 256, 0, stream>>>(ei, ea, h01, agg1, deg, E);
    finalize1_kernel<<<nb_n, 256, 0, stream>>>(agg1, deg, xr, b1, W2, root2, b2, g01, hrb, N);
    edge2_kernel<<<nb_e, 256, 0, stream>>>(ei, ea, g01, agg2, E);
    finalize2_kernel<<<(N * 10 + 255) / 256, 256, 0, stream>>>(agg2, deg, hrb, out, N);
}

// Round 3
// 323.978 us; speedup vs baseline: 7.0507x; 7.0507x over previous
//
#include <hip/hip_runtime.h>
#include <math.h>

// ---------------------------------------------------------------------------
// spline_net: 2-layer SplineConv, CSR-gather formulation (no float atomics).
//   r2 redesign: round-1 counters showed 850MB WRITE_SIZE on edge1 = 27M
//   device-scope fp32 atomics x ~32B write-through at ~680GB/s. Replace
//   scatter-atomics with per-call counting sort (CSR by dst) + gather.
// N=100000, F_IN=128, HID=16, C=10, E=1600000
// ---------------------------------------------------------------------------

// GEMM1: h01[n][0:16]=x@W1[0], h01[n][16:32]=x@W1[1], xr[n][0:16]=x@root1
__global__ __launch_bounds__(256) void gemm1_kernel(
    const float* __restrict__ x, const float* __restrict__ W1,
    const float* __restrict__ root1, float* __restrict__ h01,
    float* __restrict__ xr, int N)
{
    __shared__ float Ws[128][48];
    int tid = threadIdx.x;
    for (int idx = tid; idx < 128 * 16; idx += 256) {
        int i = idx >> 4, j = idx & 15;
        Ws[i][j]      = W1[i * 16 + j];
        Ws[i][16 + j] = W1[2048 + i * 16 + j];
        Ws[i][32 + j] = root1[i * 16 + j];
    }
    __syncthreads();
    int n = blockIdx.x * 256 + tid;
    if (n >= N) return;

    float acc[48];
#pragma unroll
    for (int j = 0; j < 48; ++j) acc[j] = 0.f;

    const float4* xrow = (const float4*)(x + (size_t)n * 128);
#pragma unroll 1
    for (int k4 = 0; k4 < 32; ++k4) {
        float4 xv = xrow[k4];
        int k = k4 * 4;
#pragma unroll
        for (int j = 0; j < 48; ++j) {
            acc[j] += xv.x * Ws[k][j] + xv.y * Ws[k + 1][j]
                    + xv.z * Ws[k + 2][j] + xv.w * Ws[k + 3][j];
        }
    }
    float4* out01 = (float4*)(h01 + (size_t)n * 32);
#pragma unroll
    for (int q = 0; q < 8; ++q)
        out01[q] = make_float4(acc[q * 4], acc[q * 4 + 1], acc[q * 4 + 2], acc[q * 4 + 3]);
    float4* outr = (float4*)(xr + (size_t)n * 16);
#pragma unroll
    for (int q = 0; q < 4; ++q)
        outr[q] = make_float4(acc[32 + q * 4], acc[33 + q * 4], acc[34 + q * 4], acc[35 + q * 4]);
}

// ---- CSR build -------------------------------------------------------------

__global__ __launch_bounds__(256) void hist_kernel(
    const int* __restrict__ ei, int* __restrict__ cnt, int E)
{
    int e = blockIdx.x * 256 + threadIdx.x;
    if (e < E) atomicAdd(&cnt[ei[E + e]], 1);
}

// exclusive scan of cnt within 256-blocks; block totals to bsum
__global__ __launch_bounds__(256) void scan1_kernel(
    const int* __restrict__ cnt, int* __restrict__ roff,
    int* __restrict__ bsum, int N)
{
    __shared__ int s[256];
    int tid = threadIdx.x;
    int i = blockIdx.x * 256 + tid;
    int v = (i < N) ? cnt[i] : 0;
    s[tid] = v;
    __syncthreads();
    for (int off = 1; off < 256; off <<= 1) {
        int t = (tid >= off) ? s[tid - off] : 0;
        __syncthreads();
        s[tid] += t;
        __syncthreads();
    }
    if (i < N) roff[i] = s[tid] - v;          // exclusive
    if (tid == 255) bsum[blockIdx.x] = s[255]; // block total
}

// exclusive scan of block sums (single block, nb <= 512)
__global__ __launch_bounds__(512) void scan2_kernel(int* __restrict__ bsum, int nb)
{
    __shared__ int s[512];
    int tid = threadIdx.x;
    int v = (tid < nb) ? bsum[tid] : 0;
    s[tid] = v;
    __syncthreads();
    for (int off = 1; off < 512; off <<= 1) {
        int t = (tid >= off) ? s[tid - off] : 0;
        __syncthreads();
        s[tid] += t;
        __syncthreads();
    }
    if (tid < nb) bsum[tid] = s[tid] - v;
}

// add block offsets; init write cursors; deg as float
__global__ __launch_bounds__(256) void scan3_kernel(
    int* __restrict__ roff, const int* __restrict__ bsum,
    const int* __restrict__ cnt, int* __restrict__ woff,
    float* __restrict__ degf, int N)
{
    int i = blockIdx.x * 256 + threadIdx.x;
    if (i >= N) return;
    int r = roff[i] + bsum[blockIdx.x];
    roff[i] = r;
    woff[i] = r;
    degf[i] = (float)cnt[i];
}

// scatter edge records {src, w1} into CSR slots
__global__ __launch_bounds__(256) void scatter_kernel(
    const int* __restrict__ ei, const float* __restrict__ ea,
    int* __restrict__ woff, int2* __restrict__ edata, int E)
{
    int e = blockIdx.x * 256 + threadIdx.x;
    if (e >= E) return;
    int s = ei[e];
    int d = ei[E + e];
    int pos = atomicAdd(&woff[d], 1);
    edata[pos] = make_int2(s, __float_as_int(ea[e]));
}

// ---- Gathers (no atomics) --------------------------------------------------

// 16 lanes per node; lane c owns channel c. msg = h0 + w*(h1-h0), summed.
__global__ __launch_bounds__(256) void gather1_kernel(
    const int2* __restrict__ edata, const int* __restrict__ roff,
    const int* __restrict__ cnt, const float* __restrict__ h01,
    float* __restrict__ agg1, int N)
{
    int t = blockIdx.x * 256 + threadIdx.x;
    int n = t >> 4;
    int c = t & 15;
    if (n >= N) return;
    int start = roff[n];
    int m = cnt[n];
    float acc = 0.f;
#pragma unroll 2
    for (int k = 0; k < m; ++k) {
        int2 r = edata[start + k];
        int s = r.x;
        float w = __int_as_float(r.y);
        float a = h01[(size_t)s * 32 + c];
        float b = h01[(size_t)s * 32 + 16 + c];
        acc += a + w * (b - a);
    }
    agg1[(size_t)n * 16 + c] = acc;
}

// layer-2 aggregation in h-space: p = sum (1-w)h[src], q = sum w*h[src]
__global__ __launch_bounds__(256) void gather2_kernel(
    const int2* __restrict__ edata, const int* __restrict__ roff,
    const int* __restrict__ cnt, const float* __restrict__ h,
    float* __restrict__ pq, int N)
{
    int t = blockIdx.x * 256 + threadIdx.x;
    int n = t >> 4;
    int c = t & 15;
    if (n >= N) return;
    int start = roff[n];
    int m = cnt[n];
    float p = 0.f, q = 0.f;
#pragma unroll 2
    for (int k = 0; k < m; ++k) {
        int2 r = edata[start + k];
        float w = __int_as_float(r.y);
        float v = h[(size_t)r.x * 16 + c];
        p += (1.f - w) * v;
        q += w * v;
    }
    pq[(size_t)n * 32 + c]      = p;
    pq[(size_t)n * 32 + 16 + c] = q;
}

// ---- Finalize --------------------------------------------------------------

// h = elu(agg1/max(deg,1) + xr + b1); hrb = h@root2 + b2
__global__ __launch_bounds__(256) void finalize1_kernel(
    const float* __restrict__ agg1, const float* __restrict__ degf,
    const float* __restrict__ xr, const float* __restrict__ b1,
    const float* __restrict__ root2, const float* __restrict__ b2,
    float* __restrict__ h, float* __restrict__ hrb, int N)
{
    __shared__ float r2s[160];
    __shared__ float b1s[16];
    __shared__ float b2s[10];
    int tid = threadIdx.x;
    if (tid < 160) r2s[tid] = root2[tid];
    if (tid < 16)  b1s[tid] = b1[tid];
    if (tid < 10)  b2s[tid] = b2[tid];
    __syncthreads();
    int n = blockIdx.x * 256 + tid;
    if (n >= N) return;

    float invd = 1.0f / fmaxf(degf[n], 1.0f);
    float hv[16];
#pragma unroll
    for (int c = 0; c < 16; ++c) {
        float v = agg1[(size_t)n * 16 + c] * invd + xr[(size_t)n * 16 + c] + b1s[c];
        hv[c] = v > 0.f ? v : expm1f(v);
    }
    float4* hp = (float4*)(h + (size_t)n * 16);
#pragma unroll
    for (int q = 0; q < 4; ++q)
        hp[q] = make_float4(hv[q * 4], hv[q * 4 + 1], hv[q * 4 + 2], hv[q * 4 + 3]);

    float hr[10];
#pragma unroll
    for (int j = 0; j < 10; ++j) hr[j] = b2s[j];
#pragma unroll
    for (int i = 0; i < 16; ++i)
#pragma unroll
        for (int j = 0; j < 10; ++j)
            hr[j] += hv[i] * r2s[i * 10 + j];
    float* hb = hrb + (size_t)n * 10;
#pragma unroll
    for (int j = 0; j < 10; ++j) hb[j] = hr[j];
}

// out = (p@W2[0] + q@W2[1])/max(deg,1) + hrb
__global__ __launch_bounds__(256) void finalize2_kernel(
    const float* __restrict__ pq, const float* __restrict__ degf,
    const float* __restrict__ hrb, const float* __restrict__ W2,
    float* __restrict__ out, int N)
{
    __shared__ float w2s[320];
    int tid = threadIdx.x;
    for (int idx = tid; idx < 320; idx += 256) w2s[idx] = W2[idx];
    __syncthreads();
    int n = blockIdx.x * 256 + tid;
    if (n >= N) return;

    float invd = 1.0f / fmaxf(degf[n], 1.0f);
    float pv[16], qv[16];
    const float4* pp = (const float4*)(pq + (size_t)n * 32);
#pragma unroll
    for (int q4 = 0; q4 < 4; ++q4) {
        float4 a = pp[q4];
        pv[q4 * 4] = a.x; pv[q4 * 4 + 1] = a.y; pv[q4 * 4 + 2] = a.z; pv[q4 * 4 + 3] = a.w;
        float4 b = pp[4 + q4];
        qv[q4 * 4] = b.x; qv[q4 * 4 + 1] = b.y; qv[q4 * 4 + 2] = b.z; qv[q4 * 4 + 3] = b.w;
    }
    float o[10];
#pragma unroll
    for (int j = 0; j < 10; ++j) o[j] = 0.f;
#pragma unroll
    for (int i = 0; i < 16; ++i)
#pragma unroll
        for (int j = 0; j < 10; ++j)
            o[j] += pv[i] * w2s[i * 10 + j] + qv[i] * w2s[160 + i * 10 + j];
    float* op = out + (size_t)n * 10;
    const float* hb = hrb + (size_t)n * 10;
#pragma unroll
    for (int j = 0; j < 10; ++j) op[j] = o[j] * invd + hb[j];
}

extern "C" void kernel_launch(void* const* d_in, const int* in_sizes, int n_in,
                              void* d_out, int out_size, void* d_ws, size_t ws_size,
                              hipStream_t stream)
{
    const float* x     = (const float*)d_in[0];
    const int*   ei    = (const int*)d_in[1];   // (2,E)
    const float* ea    = (const float*)d_in[2]; // (E,1)
    const float* W1    = (const float*)d_in[3]; // (2,128,16)
    const float* root1 = (const float*)d_in[4]; // (128,16)
    const float* b1    = (const float*)d_in[5]; // (16,)
    const float* W2    = (const float*)d_in[6]; // (2,16,10)
    const float* root2 = (const float*)d_in[7]; // (16,10)
    const float* b2    = (const float*)d_in[8]; // (10,)
    float* out = (float*)d_out;

    int N = in_sizes[0] / 128;
    int E = in_sizes[2];

    // workspace layout (~50.5 MB). pq aliases h01 (dead after gather1).
    char* ws = (char*)d_ws;
    int2*  edata = (int2*)ws;                         // E*8B = 12.8MB
    float* h01   = (float*)(ws + (size_t)E * 8);      // N*32 (later reused as pq)
    float* pq    = h01;
    float* xr    = h01  + (size_t)N * 32;             // N*16
    float* agg1  = xr   + (size_t)N * 16;             // N*16
    float* h     = agg1 + (size_t)N * 16;             // N*16
    float* hrb   = h    + (size_t)N * 16;             // N*10
    float* degf  = hrb  + (size_t)N * 10;             // N
    int*   cnt   = (int*)(degf + N);                  // N
    int*   roff  = cnt  + N;                          // N
    int*   woff  = roff + N;                          // N
    int*   bsum  = woff + N;                          // 512

    int nb_n = (N + 255) / 256;         // 391
    int nb_e = (E + 255) / 256;         // 6250
    int nb_g = (N * 16 + 255) / 256;    // 6250

    hipMemsetAsync(cnt, 0, (size_t)N * sizeof(int), stream);

    gemm1_kernel  <<<nb_n, 256, 0, stream>>>(x, W1, root1, h01, xr, N);
    hist_kernel   <<<nb_e, 256, 0, stream>>>(ei, cnt, E);
    scan1_kernel  <<<nb_n, 256, 0, stream>>>(cnt, roff, bsum, N);
    scan2_kernel  <<<1, 512, 0, stream>>>(bsum, nb_n);
    scan3_kernel  <<<nb_n, 256, 0, stream>>>(roff, bsum, cnt, woff, degf, N);
    scatter_kernel<<<nb_e, 256, 0, stream>>>(ei, ea, woff, edata, E);
    gather1_kernel<<<nb_g, 256, 0, stream>>>(edata, roff, cnt, h01, agg1, N);
    finalize1_kernel<<<nb_n, 256, 0, stream>>>(agg1, degf, xr, b1, root2, b2, h, hrb, N);
    gather2_kernel<<<nb_g, 256, 0, stream>>>(edata, roff, cnt, h, pq, N);
    finalize2_kernel<<<nb_n, 256, 0, stream>>>(pq, degf, hrb, W2, out, N);
}